// Round 9
// baseline (1017.810 us; speedup 1.0000x reference)
//
#include <hip/hip_runtime.h>

// GraphSAGE 2-layer inference, MI355X — round 9.
// = round 8 plus:
//   - CSR fill restructured: bucket-scatter (64 rows/bucket, packed 4B words,
//     exact offsets from rowptr) + per-bucket LDS-cursor fill. Kills the 197MB
//     write amplification of the old one-shot atomic scatter.
//   - layer-2 P path in fp8(e4m3), permuted column layout (col n*16+li at byte
//     li*8+n) so MFMA epilogue packs 8B/store and gather reads 128B rows.
// Inputs: x[N,256] f32, edge_src[E] i32, edge_dst[E] i32, edge_val[E] f32 (unused; recomputed),
//         W1[512,256] f32, b1[256] f32, W2[512,128] f32, b2[128] f32.
// Output: [N,128] f32 (row L2-normalized).

#define N_NODES 100000
#define N_EDGES 3200000
#define DF      256          // feature dim (D_IN == D_HID)
#define NBUCK   ((N_NODES + 63) / 64)   // 1563 buckets of 64 rows

typedef __bf16 bf16x8 __attribute__((ext_vector_type(8)));
typedef float  f32x4  __attribute__((ext_vector_type(4)));
typedef float  f32x2  __attribute__((ext_vector_type(2)));

__device__ __forceinline__ ushort f2bf(float f){   // RTNE f32 -> bf16
  uint u = __float_as_uint(f);
  u += 0x7fffu + ((u >> 16) & 1u);
  return (ushort)(u >> 16);
}
__device__ __forceinline__ float bflo(uint u){ return __uint_as_float(u << 16); }
__device__ __forceinline__ float bfhi(uint u){ return __uint_as_float(u & 0xffff0000u); }

// ------------------------- CSR build -------------------------

__global__ void k_hist(const int* __restrict__ src, int* __restrict__ deg, int E){
  int i = blockIdx.x * blockDim.x + threadIdx.x;
  if(i < E) atomicAdd(&deg[__builtin_nontemporal_load(&src[i])], 1);
}

__global__ void k_scan1(const int* __restrict__ deg, int* __restrict__ rowptr,
                        int* __restrict__ partials, int n){
  __shared__ int s[256];
  const int t = threadIdx.x;
  const int base = blockIdx.x * 1024 + t * 4;
  int v[4], run[4];
  #pragma unroll
  for(int j = 0; j < 4; j++) v[j] = (base + j < n) ? deg[base + j] : 0;
  int sum = 0;
  #pragma unroll
  for(int j = 0; j < 4; j++){ run[j] = sum; sum += v[j]; }
  s[t] = sum;
  __syncthreads();
  for(int off = 1; off < 256; off <<= 1){
    int x = (t >= off) ? s[t - off] : 0;
    __syncthreads();
    s[t] += x;
    __syncthreads();
  }
  const int texcl = s[t] - sum;
  #pragma unroll
  for(int j = 0; j < 4; j++) if(base + j < n) rowptr[base + j] = texcl + run[j];
  if(t == 255) partials[blockIdx.x] = s[255];
}

__global__ void k_scan2(int* __restrict__ partials, int nb,
                        int* __restrict__ rowptr, int n, int E){
  __shared__ int s[128];
  const int t = threadIdx.x;
  int v = (t < nb) ? partials[t] : 0;
  s[t] = v;
  __syncthreads();
  for(int off = 1; off < 128; off <<= 1){
    int x = (t >= off) ? s[t - off] : 0;
    __syncthreads();
    s[t] += x;
    __syncthreads();
  }
  if(t < nb) partials[t] = s[t] - v;
  if(t == 0) rowptr[n] = E;
}

__global__ void k_scan3(int* __restrict__ rowptr, const int* __restrict__ partials, int n){
  int i = blockIdx.x * blockDim.x + threadIdx.x;
  if(i < n) rowptr[i] += partials[i >> 10];
}

// Pass 1: scatter edges into row-ordered bucket queue. Bucket b = src>>6 owns
// bq[rowptr[b*64] .. rowptr[(b+1)*64]) — exact capacity, offsets free from rowptr.
// Packed word: dst (17b) | (src&63)<<17. NT loads keep edge streams out of L2.
__global__ void k_bucket(const int* __restrict__ esrc, const int* __restrict__ edst,
                         const int* __restrict__ rowptr, int* __restrict__ bcur,
                         uint* __restrict__ bq, int E){
  int i = blockIdx.x * blockDim.x + threadIdx.x;
  if(i < E){
    const int s = __builtin_nontemporal_load(&esrc[i]);
    const int d = __builtin_nontemporal_load(&edst[i]);
    const int base = rowptr[s & ~63];
    const int p = atomicAdd(&bcur[s >> 6], 1);
    bq[base + p] = (uint)d | ((uint)(s & 63) << 17);
  }
}

// Pass 2: one block per bucket. LDS row-cursors; colidx writes land in the
// bucket's contiguous ~8KB window -> each line completes while L2-resident.
__global__ __launch_bounds__(256)
void k_fillb(const uint* __restrict__ bq, const int* __restrict__ rowptr,
             int* __restrict__ colidx, int Nn){
  __shared__ int rp[65];
  __shared__ int lcur[64];
  const int t  = threadIdx.x;
  const int r0 = blockIdx.x << 6;
  if(t < 65) rp[t] = rowptr[min(r0 + t, Nn)];
  if(t < 64) lcur[t] = 0;
  __syncthreads();
  const int base = rp[0];
  const int cnt  = rp[min(64, Nn - r0)] - base;
  for(int e = t; e < cnt; e += 256){
    const uint w = __builtin_nontemporal_load(&bq[base + e]);
    const int li = (int)(w >> 17);
    const int d  = (int)(w & 0x1FFFFu);
    const int p  = atomicAdd(&lcur[li], 1);
    colidx[rp[li] + p] = d;
  }
}

// ------------- f32 -> bf16 + fp8(e4m3) mirrors (+ zero deg/bcur) -------------

__global__ void k_cvt(const float4* __restrict__ x4, uint4* __restrict__ outb,
                      uint2* __restrict__ outq, int n8,
                      int* __restrict__ za, int nza, int* __restrict__ zb, int nzb){
  int i = blockIdx.x * blockDim.x + threadIdx.x;
  if(i < nza) za[i] = 0;
  if(i < nzb) zb[i] = 0;
  if(i >= n8) return;
  const float4 p = x4[2*i], q = x4[2*i+1];
  uint4 o;
  o.x = (uint)f2bf(p.x) | ((uint)f2bf(p.y) << 16);
  o.y = (uint)f2bf(p.z) | ((uint)f2bf(p.w) << 16);
  o.z = (uint)f2bf(q.x) | ((uint)f2bf(q.y) << 16);
  o.w = (uint)f2bf(q.z) | ((uint)f2bf(q.w) << 16);
  outb[i] = o;
  uint w0 = __builtin_amdgcn_cvt_pk_fp8_f32(p.x, p.y, 0u, false);
  w0      = __builtin_amdgcn_cvt_pk_fp8_f32(p.z, p.w, w0, true);
  uint w1 = __builtin_amdgcn_cvt_pk_fp8_f32(q.x, q.y, 0u, false);
  w1      = __builtin_amdgcn_cvt_pk_fp8_f32(q.z, q.w, w1, true);
  outq[i] = make_uint2(w0, w1);
}

// ------------------------- W fragment pack -------------------------
// B-fragment for mfma_f32_16x16x32_bf16: lane l holds B[k0+(l>>4)*8+i][col0+(l&15)], i=0..7.

template<int DOUT>
__global__ void k_packw(const float* __restrict__ W, uint4* __restrict__ Wp,
                        int ksteps, int krow0){
  constexpr int NT = DOUT / 16;
  const int tid = blockIdx.x * blockDim.x + threadIdx.x;
  if(tid >= NT * ksteps * 64) return;
  const int l   = tid & 63;
  const int s   = (tid >> 6) % ksteps;
  const int n   = tid / (64 * ksteps);
  const int grp = l >> 4, li = l & 15;
  const int col = n * 16 + li;
  ushort b[8];
  #pragma unroll
  for(int i = 0; i < 8; i++){
    const int k = krow0 + s * 32 + grp * 8 + i;
    b[i] = f2bf(W[(size_t)k * DOUT + col]);
  }
  uint4 o;
  o.x = (uint)b[0] | ((uint)b[1] << 16);
  o.y = (uint)b[2] | ((uint)b[3] << 16);
  o.z = (uint)b[4] | ((uint)b[5] << 16);
  o.w = (uint)b[6] | ((uint)b[7] << 16);
  Wp[tid] = o;
}

// ------------------ gather from fp8 table (mean -> bf16, elementwise) ------------------
// One wave per node; RB = row bytes (256 or 128). LPR = RB/16 lanes per row,
// EPG = 64/LPR edges per group, 4 uint4 loads in flight. v_cvt_pk_f32_fp8 decode.
// Output: bf16 row of RB elements at the SAME byte-position order (layout-agnostic).

template<int RB>
__global__ __launch_bounds__(256)
void k_gather_q(const uchar* __restrict__ xq, const int* __restrict__ rowptr,
                const int* __restrict__ colidx, ushort* __restrict__ nbuf, int Nn){
  constexpr int LPR = RB / 16;
  constexpr int EPG = 64 / LPR;
  const int node = (blockIdx.x * blockDim.x + threadIdx.x) >> 6;
  const int lane = threadIdx.x & 63;
  if(node >= Nn) return;
  const int half = lane / LPR;
  const int li   = lane % LPR;
  const int s0 = rowptr[node];
  const int s1 = rowptr[node + 1];
  const float invd = (s1 > s0) ? (1.0f / (float)(s1 - s0)) : 0.0f;
  const uint cmax = (uint)(Nn - 1);
  float a[16];
  #pragma unroll
  for(int i = 0; i < 16; i++) a[i] = 0.f;

  #define DECODE_ACC(v)                                                        \
    {                                                                          \
      const uint uu[4] = {(v).x, (v).y, (v).z, (v).w};                         \
      _Pragma("unroll")                                                        \
      for(int m = 0; m < 4; m++){                                              \
        f32x2 lo = __builtin_amdgcn_cvt_pk_f32_fp8(uu[m], false);              \
        f32x2 hi = __builtin_amdgcn_cvt_pk_f32_fp8(uu[m], true);               \
        a[m*4+0] += lo.x; a[m*4+1] += lo.y;                                    \
        a[m*4+2] += hi.x; a[m*4+3] += hi.y;                                    \
      }                                                                        \
    }

  int e = s0;
  for(; e + 4 * EPG <= s1; e += 4 * EPG){
    uint c[4];
    #pragma unroll
    for(int j = 0; j < 4; j++)
      c[j] = min((uint)__builtin_nontemporal_load(&colidx[e + j * EPG + half]), cmax);
    uint4 v[4];
    #pragma unroll
    for(int j = 0; j < 4; j++) v[j] = *(const uint4*)(xq + (size_t)c[j] * RB + li * 16);
    #pragma unroll
    for(int j = 0; j < 4; j++) DECODE_ACC(v[j]);
  }
  for(; e + EPG <= s1; e += EPG){
    const uint c = min((uint)__builtin_nontemporal_load(&colidx[e + half]), cmax);
    const uint4 v = *(const uint4*)(xq + (size_t)c * RB + li * 16);
    DECODE_ACC(v);
  }
  if(half < s1 - e){
    const uint c = min((uint)__builtin_nontemporal_load(&colidx[e + half]), cmax);
    const uint4 v = *(const uint4*)(xq + (size_t)c * RB + li * 16);
    DECODE_ACC(v);
  }
  #undef DECODE_ACC

  #pragma unroll
  for(int off = LPR; off < 64; off <<= 1)
    #pragma unroll
    for(int i = 0; i < 16; i++) a[i] += __shfl_xor(a[i], off);

  if(lane < LPR){
    uint4 o1, o2;
    o1.x = (uint)f2bf(a[ 0]*invd) | ((uint)f2bf(a[ 1]*invd) << 16);
    o1.y = (uint)f2bf(a[ 2]*invd) | ((uint)f2bf(a[ 3]*invd) << 16);
    o1.z = (uint)f2bf(a[ 4]*invd) | ((uint)f2bf(a[ 5]*invd) << 16);
    o1.w = (uint)f2bf(a[ 6]*invd) | ((uint)f2bf(a[ 7]*invd) << 16);
    o2.x = (uint)f2bf(a[ 8]*invd) | ((uint)f2bf(a[ 9]*invd) << 16);
    o2.y = (uint)f2bf(a[10]*invd) | ((uint)f2bf(a[11]*invd) << 16);
    o2.z = (uint)f2bf(a[12]*invd) | ((uint)f2bf(a[13]*invd) << 16);
    o2.w = (uint)f2bf(a[14]*invd) | ((uint)f2bf(a[15]*invd) << 16);
    ushort* p = nbuf + (size_t)node * RB + li * 16;
    *(uint4*)(p)     = o1;
    *(uint4*)(p + 8) = o2;
  }
}

// ------------------------- MFMA MLP / projection -------------------------
// Per wave: 16 nodes. A-frag lane l holds A[l&15][s*32+(l>>4)*8+i]. TWOSRC: first
// KS/2 k-steps from A0, rest from A1 (concat). B from Wp (L2-hot). C layout:
// col=lane&15, row=(lane>>4)*4+reg. OMODE: 0=f32, 1=bf16, 2=fp8 permuted
// (col n*16+li stored at byte li*8+n -> one 8B store per row-fragment).
// ADDG adds gathered bf16 term in the SAME permuted layout (uint4 per row).

template<int DOUT, int KS, bool TWOSRC, bool ADDG, bool RELU, bool NORM, int OMODE>
__launch_bounds__(256, 2)
__global__ void k_mlp(const ushort* __restrict__ A0, const ushort* __restrict__ A1,
                      const uint4* __restrict__ Wp, const float* __restrict__ bias,
                      const ushort* __restrict__ g,
                      void* __restrict__ outp, int Nn)
{
  constexpr int NT   = DOUT / 16;
  constexpr int DIMA = TWOSRC ? KS * 16 : KS * 32;
  const int l     = threadIdx.x & 63;
  const int w     = threadIdx.x >> 6;
  const int nodeb = blockIdx.x * 64 + w * 16;
  const int grp   = l >> 4;
  const int li    = l & 15;

  const int rowL = min(nodeb + li, Nn - 1);
  uint4 a[KS];
  if(TWOSRC){
    const ushort* xr = A0 + (size_t)rowL * DIMA;
    const ushort* nr = A1 + (size_t)rowL * DIMA;
    #pragma unroll
    for(int s = 0; s < KS/2; s++) a[s]        = *(const uint4*)(xr + s * 32 + grp * 8);
    #pragma unroll
    for(int s = 0; s < KS/2; s++) a[s + KS/2] = *(const uint4*)(nr + s * 32 + grp * 8);
  } else {
    const ushort* xr = A0 + (size_t)rowL * DIMA;
    #pragma unroll
    for(int s = 0; s < KS; s++) a[s] = *(const uint4*)(xr + s * 32 + grp * 8);
  }

  f32x4 acc[NT];
  #pragma unroll
  for(int n = 0; n < NT; n++){
    f32x4 c = {0.f, 0.f, 0.f, 0.f};
    #pragma unroll
    for(int s = 0; s < KS; s++){
      const uint4 b = Wp[(size_t)(n * KS + s) * 64 + l];
      c = __builtin_amdgcn_mfma_f32_16x16x32_bf16(
            __builtin_bit_cast(bf16x8, a[s]),
            __builtin_bit_cast(bf16x8, b), c, 0, 0, 0);
    }
    acc[n] = c;
  }

  if(NORM){
    #pragma unroll
    for(int n = 0; n < NT; n++){
      const float bv = bias[n * 16 + li];
      acc[n][0] += bv; acc[n][1] += bv; acc[n][2] += bv; acc[n][3] += bv;
    }
  }

  if(ADDG){   // permuted layout: byte j=li*8+n <-> col n*16+li; 8 bf16 = one uint4
    #pragma unroll
    for(int r = 0; r < 4; r++){
      const int rowg = min(nodeb + grp * 4 + r, Nn - 1);
      const uint4 gv = *(const uint4*)(g + (size_t)rowg * DOUT + li * 8);
      acc[0][r] += bflo(gv.x); acc[1][r] += bfhi(gv.x);
      acc[2][r] += bflo(gv.y); acc[3][r] += bfhi(gv.y);
      acc[4][r] += bflo(gv.z); acc[5][r] += bfhi(gv.z);
      acc[6][r] += bflo(gv.w); acc[7][r] += bfhi(gv.w);
    }
  }

  float rn[4] = {1.f, 1.f, 1.f, 1.f};
  if(NORM){
    #pragma unroll
    for(int r = 0; r < 4; r++){
      float ss = 0.f;
      #pragma unroll
      for(int n = 0; n < NT; n++) ss = fmaf(acc[n][r], acc[n][r], ss);
      ss += __shfl_xor(ss, 1);
      ss += __shfl_xor(ss, 2);
      ss += __shfl_xor(ss, 4);
      ss += __shfl_xor(ss, 8);
      rn[r] = 1.0f / fmaxf(sqrtf(ss), 1e-12f);
    }
  }

  #pragma unroll
  for(int r = 0; r < 4; r++){
    const int node = nodeb + grp * 4 + r;
    if(node < Nn){
      if(OMODE == 2){   // fp8, permuted: 8 cols -> 8 consecutive bytes
        uint w0 = __builtin_amdgcn_cvt_pk_fp8_f32(acc[0][r], acc[1][r], 0u, false);
        w0      = __builtin_amdgcn_cvt_pk_fp8_f32(acc[2][r], acc[3][r], w0, true);
        uint w1 = __builtin_amdgcn_cvt_pk_fp8_f32(acc[4][r], acc[5][r], 0u, false);
        w1      = __builtin_amdgcn_cvt_pk_fp8_f32(acc[6][r], acc[7][r], w1, true);
        *(uint2*)((uchar*)outp + (size_t)node * DOUT + li * 8) = make_uint2(w0, w1);
      } else {
        #pragma unroll
        for(int n = 0; n < NT; n++){
          float y = acc[n][r];
          if(NORM) y *= rn[r];
          if(RELU) y = fmaxf(y, 0.0f);
          const size_t idx = (size_t)node * DOUT + n * 16 + li;
          if(OMODE == 1) ((ushort*)outp)[idx] = f2bf(y);
          else           ((float*)outp)[idx]  = y;
        }
      }
    }
  }
}

// ------------------------- host launch -------------------------

extern "C" void kernel_launch(void* const* d_in, const int* in_sizes, int n_in,
                              void* d_out, int out_size, void* d_ws, size_t ws_size,
                              hipStream_t stream) {
  const float* x    = (const float*)d_in[0];
  const int*   esrc = (const int*)  d_in[1];
  const int*   edst = (const int*)  d_in[2];
  // d_in[3] edge_val unused — it equals 1/deg(src), recomputed from CSR
  const float* W1   = (const float*)d_in[4];
  const float* b1   = (const float*)d_in[5];
  const float* W2   = (const float*)d_in[6];
  const float* b2   = (const float*)d_in[7];
  float* out = (float*)d_out;

  const int N = N_NODES, E = N_EDGES;

  char* ws = (char*)d_ws;
  size_t off = 0;
  auto alloc = [&](size_t bytes) -> void* {
    void* p = ws + off;
    off += (bytes + 255) & ~(size_t)255;
    return p;
  };
  int*    deg      = (int*)   alloc((size_t)N * 4);
  int*    rowptr   = (int*)   alloc((size_t)(N + 1) * 4);
  int*    bcur     = (int*)   alloc((size_t)NBUCK * 4);
  int*    partials = (int*)   alloc(512);
  int*    colidx   = (int*)   alloc((size_t)E * 4);
  uint*   bq       = (uint*)  alloc((size_t)E * 4);        // bucket queue (packed)
  ushort* xbuf     = (ushort*)alloc((size_t)N * DF * 2);   // bf16 mirror of x
  uchar*  xq       = (uchar*) alloc((size_t)N * DF);       // fp8 e4m3 mirror of x
  ushort* hbuf     = (ushort*)alloc((size_t)N * DF * 2);   // bf16 h (layer-1 out)
  ushort* nbuf     = (ushort*)alloc((size_t)N * DF * 2);   // layer1 neigh; reused as Pq|gb
  uint4*  Wp1      = (uint4*) alloc((size_t)16 * 16 * 64 * 16);  // W1: NT=16, KS=16
  uint4*  Wp2a     = (uint4*) alloc((size_t) 8 *  8 * 64 * 16);  // W2 rows 0..255
  uint4*  Wp2b     = (uint4*) alloc((size_t) 8 *  8 * 64 * 16);  // W2 rows 256..511
  if(off > ws_size) return;   // ~206 MB; round-3 proved ws >= ~219 MB

  uchar*  Pq = (uchar*)nbuf;                         // [N,128] fp8, permuted cols
  ushort* gb = nbuf + (size_t)N * 64;                // [N,128] bf16 gathered P (N*128B offset)

  const int NBLK_SCAN = (N + 1023) / 1024;   // 98
  const int n8 = N * DF / 8;

  // mirrors of x + zero deg/bcur in one pass
  k_cvt<<<(n8 + 255) / 256, 256, 0, stream>>>((const float4*)x, (uint4*)xbuf,
                                              (uint2*)xq, n8, deg, N, bcur, NBUCK);
  k_packw<256><<<(16 * 16 * 64 + 255) / 256, 256, 0, stream>>>(W1,  Wp1, 16, 0);
  k_packw<128><<<( 8 *  8 * 64 + 255) / 256, 256, 0, stream>>>(W2, Wp2a,  8, 0);
  k_packw<128><<<( 8 *  8 * 64 + 255) / 256, 256, 0, stream>>>(W2, Wp2b,  8, 256);

  // CSR: hist -> scan -> bucket-scatter -> bucket-local fill
  k_hist  <<<(E + 255) / 256, 256, 0, stream>>>(esrc, deg, E);
  k_scan1 <<<NBLK_SCAN,       256, 0, stream>>>(deg, rowptr, partials, N);
  k_scan2 <<<1,               128, 0, stream>>>(partials, NBLK_SCAN, rowptr, N, E);
  k_scan3 <<<(N + 255) / 256, 256, 0, stream>>>(rowptr, partials, N);
  k_bucket<<<(E + 255) / 256, 256, 0, stream>>>(esrc, edst, rowptr, bcur, bq, E);
  k_fillb <<<NBUCK,           256, 0, stream>>>(bq, rowptr, colidx, N);

  const int GRID_MLP = (N + 63) / 64;   // 1563, tail-guarded

  // ---- layer 1: h = relu(normalize([x | mean_fp8(x)] @ W1 + b1))
  k_gather_q<256><<<N / 4, 256, 0, stream>>>(xq, rowptr, colidx, nbuf, N);
  k_mlp<256, 16, true, false, true, true, 1>
      <<<GRID_MLP, 256, 0, stream>>>(xbuf, nbuf, Wp1, b1, nullptr, hbuf, N);

  // ---- layer 2 (project-then-aggregate, P in fp8 permuted layout):
  //   P = h @ W2_bot ; out = normalize(h @ W2_top + mean_fp8(P) + b2)
  k_mlp<128, 8, false, false, false, false, 2>
      <<<GRID_MLP, 256, 0, stream>>>(hbuf, nullptr, Wp2b, nullptr, nullptr, Pq, N);
  k_gather_q<128><<<N / 4, 256, 0, stream>>>(Pq, rowptr, colidx, gb, N);
  k_mlp<128, 8, false, true, false, true, 0>
      <<<GRID_MLP, 256, 0, stream>>>(hbuf, nullptr, Wp2a, b2, gb, out, N);
}

// Round 10
// 688.598 us; speedup vs baseline: 1.4781x; 1.4781x over previous
//
#include <hip/hip_runtime.h>

// GraphSAGE 2-layer inference, MI355X — round 10.
// = round 8 CSR fill (direct atomic, proven) split into 4 src-range passes for
//   L2 write locality; round 9's fp8 P path kept; hist fused into cvt; packw
//   trio fused into one dispatch. Bucket scatter (round 9) reverted — it was
//   atomic-convoy-bound (1563 counters x 2048 edges).
// Inputs: x[N,256] f32, edge_src[E] i32, edge_dst[E] i32, edge_val[E] f32 (unused; recomputed),
//         W1[512,256] f32, b1[256] f32, W2[512,128] f32, b2[128] f32.
// Output: [N,128] f32 (row L2-normalized).

#define N_NODES 100000
#define N_EDGES 3200000
#define DF      256          // feature dim (D_IN == D_HID)
#define NRANGE  4            // src-range passes for the CSR fill

typedef __bf16 bf16x8 __attribute__((ext_vector_type(8)));
typedef float  f32x4  __attribute__((ext_vector_type(4)));
typedef float  f32x2  __attribute__((ext_vector_type(2)));

__device__ __forceinline__ ushort f2bf(float f){   // RTNE f32 -> bf16
  uint u = __float_as_uint(f);
  u += 0x7fffu + ((u >> 16) & 1u);
  return (ushort)(u >> 16);
}
__device__ __forceinline__ float bflo(uint u){ return __uint_as_float(u << 16); }
__device__ __forceinline__ float bfhi(uint u){ return __uint_as_float(u & 0xffff0000u); }

// ------------------------- zero (deg + cursor) -------------------------

__global__ void k_zero(int* __restrict__ a, int* __restrict__ b, int n){
  int i = blockIdx.x * blockDim.x + threadIdx.x;
  if(i < n){ a[i] = 0; b[i] = 0; }
}

// -------- f32 -> bf16 + fp8 mirrors, fused with degree histogram --------
// n8 == E == 3.2M: thread i converts 8-elem chunk i AND histograms edge i.

__global__ void k_cvth(const float4* __restrict__ x4, uint4* __restrict__ outb,
                       uint2* __restrict__ outq, int n8,
                       const int* __restrict__ esrc, int* __restrict__ deg, int E){
  int i = blockIdx.x * blockDim.x + threadIdx.x;
  if(i < E) atomicAdd(&deg[esrc[i]], 1);
  if(i >= n8) return;
  const float4 p = x4[2*i], q = x4[2*i+1];
  uint4 o;
  o.x = (uint)f2bf(p.x) | ((uint)f2bf(p.y) << 16);
  o.y = (uint)f2bf(p.z) | ((uint)f2bf(p.w) << 16);
  o.z = (uint)f2bf(q.x) | ((uint)f2bf(q.y) << 16);
  o.w = (uint)f2bf(q.z) | ((uint)f2bf(q.w) << 16);
  outb[i] = o;
  uint w0 = __builtin_amdgcn_cvt_pk_fp8_f32(p.x, p.y, 0u, false);
  w0      = __builtin_amdgcn_cvt_pk_fp8_f32(p.z, p.w, w0, true);
  uint w1 = __builtin_amdgcn_cvt_pk_fp8_f32(q.x, q.y, 0u, false);
  w1      = __builtin_amdgcn_cvt_pk_fp8_f32(q.z, q.w, w1, true);
  outq[i] = make_uint2(w0, w1);
}

// ------------------------- CSR scan -------------------------

__global__ void k_scan1(const int* __restrict__ deg, int* __restrict__ rowptr,
                        int* __restrict__ partials, int n){
  __shared__ int s[256];
  const int t = threadIdx.x;
  const int base = blockIdx.x * 1024 + t * 4;
  int v[4], run[4];
  #pragma unroll
  for(int j = 0; j < 4; j++) v[j] = (base + j < n) ? deg[base + j] : 0;
  int sum = 0;
  #pragma unroll
  for(int j = 0; j < 4; j++){ run[j] = sum; sum += v[j]; }
  s[t] = sum;
  __syncthreads();
  for(int off = 1; off < 256; off <<= 1){
    int x = (t >= off) ? s[t - off] : 0;
    __syncthreads();
    s[t] += x;
    __syncthreads();
  }
  const int texcl = s[t] - sum;
  #pragma unroll
  for(int j = 0; j < 4; j++) if(base + j < n) rowptr[base + j] = texcl + run[j];
  if(t == 255) partials[blockIdx.x] = s[255];
}

__global__ void k_scan2(int* __restrict__ partials, int nb,
                        int* __restrict__ rowptr, int n, int E){
  __shared__ int s[128];
  const int t = threadIdx.x;
  int v = (t < nb) ? partials[t] : 0;
  s[t] = v;
  __syncthreads();
  for(int off = 1; off < 128; off <<= 1){
    int x = (t >= off) ? s[t - off] : 0;
    __syncthreads();
    s[t] += x;
    __syncthreads();
  }
  if(t < nb) partials[t] = s[t] - v;
  if(t == 0) rowptr[n] = E;
}

__global__ void k_scan3(int* __restrict__ rowptr, const int* __restrict__ partials, int n){
  int i = blockIdx.x * blockDim.x + threadIdx.x;
  if(i < n) rowptr[i] += partials[i >> 10];
}

// ---------------- CSR fill: direct atomic scatter, src-ranged ----------------
// Pass r handles src in [lo,hi): live colidx window ~3.2MB stays L2-resident,
// so dirty lines evict ~once per XCD instead of ~16x (round-8 one-shot: 197MB).

__global__ void k_fill(const int* __restrict__ src, const int* __restrict__ dst,
                       const int* __restrict__ rowptr, int* __restrict__ cursor,
                       int* __restrict__ col, int E, int lo, int hi){
  int i = blockIdx.x * blockDim.x + threadIdx.x;
  if(i < E){
    const int r = src[i];
    if(r >= lo && r < hi){
      const int p = atomicAdd(&cursor[r], 1);
      col[rowptr[r] + p] = dst[i];
    }
  }
}

// ------------------------- W fragment pack (all three, one dispatch) -------------------------
// B-fragment for mfma_f32_16x16x32_bf16: lane l holds B[k0+(l>>4)*8+i][col0+(l&15)], i=0..7.

__device__ __forceinline__ void pack_frag(const float* __restrict__ W, uint4* __restrict__ Wp,
                                          int DOUT, int ksteps, int krow0, int tid){
  const int l   = tid & 63;
  const int s   = (tid >> 6) % ksteps;
  const int n   = tid / (64 * ksteps);
  const int grp = l >> 4, li = l & 15;
  const int col = n * 16 + li;
  ushort b[8];
  #pragma unroll
  for(int i = 0; i < 8; i++){
    const int k = krow0 + s * 32 + grp * 8 + i;
    b[i] = f2bf(W[(size_t)k * DOUT + col]);
  }
  uint4 o;
  o.x = (uint)b[0] | ((uint)b[1] << 16);
  o.y = (uint)b[2] | ((uint)b[3] << 16);
  o.z = (uint)b[4] | ((uint)b[5] << 16);
  o.w = (uint)b[6] | ((uint)b[7] << 16);
  Wp[tid] = o;
}

__global__ void k_packall(const float* __restrict__ W1, const float* __restrict__ W2,
                          uint4* __restrict__ Wp1, uint4* __restrict__ Wp2a,
                          uint4* __restrict__ Wp2b){
  const int tid = blockIdx.x * blockDim.x + threadIdx.x;
  if(tid < 16384)       pack_frag(W1, Wp1,  256, 16,   0, tid);           // 16*16*64
  else if(tid < 20480)  pack_frag(W2, Wp2a, 128,  8,   0, tid - 16384);   //  8* 8*64
  else if(tid < 24576)  pack_frag(W2, Wp2b, 128,  8, 256, tid - 20480);   //  8* 8*64
}

// ------------------ gather from fp8 table (mean -> bf16, elementwise) ------------------
// One wave per node; RB = row bytes (256 or 128). LPR = RB/16 lanes per row,
// EPG = 64/LPR edges per group, 4 uint4 loads in flight. v_cvt_pk_f32_fp8 decode.

template<int RB>
__global__ __launch_bounds__(256)
void k_gather_q(const uchar* __restrict__ xq, const int* __restrict__ rowptr,
                const int* __restrict__ colidx, ushort* __restrict__ nbuf, int Nn){
  constexpr int LPR = RB / 16;
  constexpr int EPG = 64 / LPR;
  const int node = (blockIdx.x * blockDim.x + threadIdx.x) >> 6;
  const int lane = threadIdx.x & 63;
  if(node >= Nn) return;
  const int half = lane / LPR;
  const int li   = lane % LPR;
  const int s0 = rowptr[node];
  const int s1 = rowptr[node + 1];
  const float invd = (s1 > s0) ? (1.0f / (float)(s1 - s0)) : 0.0f;
  const uint cmax = (uint)(Nn - 1);
  float a[16];
  #pragma unroll
  for(int i = 0; i < 16; i++) a[i] = 0.f;

  #define DECODE_ACC(v)                                                        \
    {                                                                          \
      const uint uu[4] = {(v).x, (v).y, (v).z, (v).w};                         \
      _Pragma("unroll")                                                        \
      for(int m = 0; m < 4; m++){                                              \
        f32x2 lo = __builtin_amdgcn_cvt_pk_f32_fp8(uu[m], false);              \
        f32x2 hi = __builtin_amdgcn_cvt_pk_f32_fp8(uu[m], true);               \
        a[m*4+0] += lo.x; a[m*4+1] += lo.y;                                    \
        a[m*4+2] += hi.x; a[m*4+3] += hi.y;                                    \
      }                                                                        \
    }

  int e = s0;
  for(; e + 4 * EPG <= s1; e += 4 * EPG){
    uint c[4];
    #pragma unroll
    for(int j = 0; j < 4; j++)
      c[j] = min((uint)__builtin_nontemporal_load(&colidx[e + j * EPG + half]), cmax);
    uint4 v[4];
    #pragma unroll
    for(int j = 0; j < 4; j++) v[j] = *(const uint4*)(xq + (size_t)c[j] * RB + li * 16);
    #pragma unroll
    for(int j = 0; j < 4; j++) DECODE_ACC(v[j]);
  }
  for(; e + EPG <= s1; e += EPG){
    const uint c = min((uint)__builtin_nontemporal_load(&colidx[e + half]), cmax);
    const uint4 v = *(const uint4*)(xq + (size_t)c * RB + li * 16);
    DECODE_ACC(v);
  }
  if(half < s1 - e){
    const uint c = min((uint)__builtin_nontemporal_load(&colidx[e + half]), cmax);
    const uint4 v = *(const uint4*)(xq + (size_t)c * RB + li * 16);
    DECODE_ACC(v);
  }
  #undef DECODE_ACC

  #pragma unroll
  for(int off = LPR; off < 64; off <<= 1)
    #pragma unroll
    for(int i = 0; i < 16; i++) a[i] += __shfl_xor(a[i], off);

  if(lane < LPR){
    uint4 o1, o2;
    o1.x = (uint)f2bf(a[ 0]*invd) | ((uint)f2bf(a[ 1]*invd) << 16);
    o1.y = (uint)f2bf(a[ 2]*invd) | ((uint)f2bf(a[ 3]*invd) << 16);
    o1.z = (uint)f2bf(a[ 4]*invd) | ((uint)f2bf(a[ 5]*invd) << 16);
    o1.w = (uint)f2bf(a[ 6]*invd) | ((uint)f2bf(a[ 7]*invd) << 16);
    o2.x = (uint)f2bf(a[ 8]*invd) | ((uint)f2bf(a[ 9]*invd) << 16);
    o2.y = (uint)f2bf(a[10]*invd) | ((uint)f2bf(a[11]*invd) << 16);
    o2.z = (uint)f2bf(a[12]*invd) | ((uint)f2bf(a[13]*invd) << 16);
    o2.w = (uint)f2bf(a[14]*invd) | ((uint)f2bf(a[15]*invd) << 16);
    ushort* p = nbuf + (size_t)node * RB + li * 16;
    *(uint4*)(p)     = o1;
    *(uint4*)(p + 8) = o2;
  }
}

// ------------------------- MFMA MLP / projection -------------------------
// Per wave: 16 nodes. A-frag lane l holds A[l&15][s*32+(l>>4)*8+i]. TWOSRC: first
// KS/2 k-steps from A0, rest from A1 (concat). B from Wp (L2-hot). C layout:
// col=lane&15, row=(lane>>4)*4+reg. OMODE: 0=f32, 1=bf16, 2=fp8 permuted
// (col n*16+li stored at byte li*8+n). ADDG adds gathered bf16 term (permuted).

template<int DOUT, int KS, bool TWOSRC, bool ADDG, bool RELU, bool NORM, int OMODE>
__launch_bounds__(256, 2)
__global__ void k_mlp(const ushort* __restrict__ A0, const ushort* __restrict__ A1,
                      const uint4* __restrict__ Wp, const float* __restrict__ bias,
                      const ushort* __restrict__ g,
                      void* __restrict__ outp, int Nn)
{
  constexpr int NT   = DOUT / 16;
  constexpr int DIMA = TWOSRC ? KS * 16 : KS * 32;
  const int l     = threadIdx.x & 63;
  const int w     = threadIdx.x >> 6;
  const int nodeb = blockIdx.x * 64 + w * 16;
  const int grp   = l >> 4;
  const int li    = l & 15;

  const int rowL = min(nodeb + li, Nn - 1);
  uint4 a[KS];
  if(TWOSRC){
    const ushort* xr = A0 + (size_t)rowL * DIMA;
    const ushort* nr = A1 + (size_t)rowL * DIMA;
    #pragma unroll
    for(int s = 0; s < KS/2; s++) a[s]        = *(const uint4*)(xr + s * 32 + grp * 8);
    #pragma unroll
    for(int s = 0; s < KS/2; s++) a[s + KS/2] = *(const uint4*)(nr + s * 32 + grp * 8);
  } else {
    const ushort* xr = A0 + (size_t)rowL * DIMA;
    #pragma unroll
    for(int s = 0; s < KS; s++) a[s] = *(const uint4*)(xr + s * 32 + grp * 8);
  }

  f32x4 acc[NT];
  #pragma unroll
  for(int n = 0; n < NT; n++){
    f32x4 c = {0.f, 0.f, 0.f, 0.f};
    #pragma unroll
    for(int s = 0; s < KS; s++){
      const uint4 b = Wp[(size_t)(n * KS + s) * 64 + l];
      c = __builtin_amdgcn_mfma_f32_16x16x32_bf16(
            __builtin_bit_cast(bf16x8, a[s]),
            __builtin_bit_cast(bf16x8, b), c, 0, 0, 0);
    }
    acc[n] = c;
  }

  if(NORM){
    #pragma unroll
    for(int n = 0; n < NT; n++){
      const float bv = bias[n * 16 + li];
      acc[n][0] += bv; acc[n][1] += bv; acc[n][2] += bv; acc[n][3] += bv;
    }
  }

  if(ADDG){   // permuted layout: byte j=li*8+n <-> col n*16+li; 8 bf16 = one uint4
    #pragma unroll
    for(int r = 0; r < 4; r++){
      const int rowg = min(nodeb + grp * 4 + r, Nn - 1);
      const uint4 gv = *(const uint4*)(g + (size_t)rowg * DOUT + li * 8);
      acc[0][r] += bflo(gv.x); acc[1][r] += bfhi(gv.x);
      acc[2][r] += bflo(gv.y); acc[3][r] += bfhi(gv.y);
      acc[4][r] += bflo(gv.z); acc[5][r] += bfhi(gv.z);
      acc[6][r] += bflo(gv.w); acc[7][r] += bfhi(gv.w);
    }
  }

  float rn[4] = {1.f, 1.f, 1.f, 1.f};
  if(NORM){
    #pragma unroll
    for(int r = 0; r < 4; r++){
      float ss = 0.f;
      #pragma unroll
      for(int n = 0; n < NT; n++) ss = fmaf(acc[n][r], acc[n][r], ss);
      ss += __shfl_xor(ss, 1);
      ss += __shfl_xor(ss, 2);
      ss += __shfl_xor(ss, 4);
      ss += __shfl_xor(ss, 8);
      rn[r] = 1.0f / fmaxf(sqrtf(ss), 1e-12f);
    }
  }

  #pragma unroll
  for(int r = 0; r < 4; r++){
    const int node = nodeb + grp * 4 + r;
    if(node < Nn){
      if(OMODE == 2){   // fp8, permuted: 8 cols -> 8 consecutive bytes
        uint w0 = __builtin_amdgcn_cvt_pk_fp8_f32(acc[0][r], acc[1][r], 0u, false);
        w0      = __builtin_amdgcn_cvt_pk_fp8_f32(acc[2][r], acc[3][r], w0, true);
        uint w1 = __builtin_amdgcn_cvt_pk_fp8_f32(acc[4][r], acc[5][r], 0u, false);
        w1      = __builtin_amdgcn_cvt_pk_fp8_f32(acc[6][r], acc[7][r], w1, true);
        *(uint2*)((uchar*)outp + (size_t)node * DOUT + li * 8) = make_uint2(w0, w1);
      } else {
        #pragma unroll
        for(int n = 0; n < NT; n++){
          float y = acc[n][r];
          if(NORM) y *= rn[r];
          if(RELU) y = fmaxf(y, 0.0f);
          const size_t idx = (size_t)node * DOUT + n * 16 + li;
          if(OMODE == 1) ((ushort*)outp)[idx] = f2bf(y);
          else           ((float*)outp)[idx]  = y;
        }
      }
    }
  }
}

// ------------------------- host launch -------------------------

extern "C" void kernel_launch(void* const* d_in, const int* in_sizes, int n_in,
                              void* d_out, int out_size, void* d_ws, size_t ws_size,
                              hipStream_t stream) {
  const float* x    = (const float*)d_in[0];
  const int*   esrc = (const int*)  d_in[1];
  const int*   edst = (const int*)  d_in[2];
  // d_in[3] edge_val unused — it equals 1/deg(src), recomputed from CSR
  const float* W1   = (const float*)d_in[4];
  const float* b1   = (const float*)d_in[5];
  const float* W2   = (const float*)d_in[6];
  const float* b2   = (const float*)d_in[7];
  float* out = (float*)d_out;

  const int N = N_NODES, E = N_EDGES;

  char* ws = (char*)d_ws;
  size_t off = 0;
  auto alloc = [&](size_t bytes) -> void* {
    void* p = ws + off;
    off += (bytes + 255) & ~(size_t)255;
    return p;
  };
  int*    deg      = (int*)   alloc((size_t)N * 4);
  int*    rowptr   = (int*)   alloc((size_t)(N + 1) * 4);
  int*    cursor   = (int*)   alloc((size_t)N * 4);
  int*    partials = (int*)   alloc(512);
  int*    colidx   = (int*)   alloc((size_t)E * 4);
  ushort* xbuf     = (ushort*)alloc((size_t)N * DF * 2);   // bf16 mirror of x
  uchar*  xq       = (uchar*) alloc((size_t)N * DF);       // fp8 e4m3 mirror of x
  ushort* hbuf     = (ushort*)alloc((size_t)N * DF * 2);   // bf16 h (layer-1 out)
  ushort* nbuf     = (ushort*)alloc((size_t)N * DF * 2);   // layer1 neigh; reused as Pq|gb
  uint4*  Wp1      = (uint4*) alloc((size_t)16 * 16 * 64 * 16);  // W1: NT=16, KS=16
  uint4*  Wp2a     = (uint4*) alloc((size_t) 8 *  8 * 64 * 16);  // W2 rows 0..255
  uint4*  Wp2b     = (uint4*) alloc((size_t) 8 *  8 * 64 * 16);  // W2 rows 256..511
  if(off > ws_size) return;

  uchar*  Pq = (uchar*)nbuf;                 // [N,128] fp8, permuted cols
  ushort* gb = nbuf + (size_t)N * 64;        // [N,128] bf16 gathered P

  const int NBLK_SCAN = (N + 1023) / 1024;   // 98
  const int n8 = N * DF / 8;                 // == E == 3.2M

  // zero counters, then mirrors-of-x fused with degree histogram
  k_zero <<<(N + 255) / 256, 256, 0, stream>>>(deg, cursor, N);
  k_cvth <<<(n8 + 255) / 256, 256, 0, stream>>>((const float4*)x, (uint4*)xbuf,
                                                (uint2*)xq, n8, esrc, deg, E);
  k_packall<<<96, 256, 0, stream>>>(W1, W2, Wp1, Wp2a, Wp2b);

  // CSR: scan then src-ranged direct fill
  k_scan1<<<NBLK_SCAN,       256, 0, stream>>>(deg, rowptr, partials, N);
  k_scan2<<<1,               128, 0, stream>>>(partials, NBLK_SCAN, rowptr, N, E);
  k_scan3<<<(N + 255) / 256, 256, 0, stream>>>(rowptr, partials, N);
  const int RSPAN = N / NRANGE;   // 25000
  for(int r = 0; r < NRANGE; r++)
    k_fill<<<(E + 255) / 256, 256, 0, stream>>>(esrc, edst, rowptr, cursor, colidx,
                                                E, r * RSPAN, (r + 1) * RSPAN);

  const int GRID_MLP = (N + 63) / 64;   // 1563, tail-guarded

  // ---- layer 1: h = relu(normalize([x | mean_fp8(x)] @ W1 + b1))
  k_gather_q<256><<<N / 4, 256, 0, stream>>>(xq, rowptr, colidx, nbuf, N);
  k_mlp<256, 16, true, false, true, true, 1>
      <<<GRID_MLP, 256, 0, stream>>>(xbuf, nbuf, Wp1, b1, nullptr, hbuf, N);

  // ---- layer 2 (project-then-aggregate, P in fp8 permuted layout):
  //   P = h @ W2_bot ; out = normalize(h @ W2_top + mean_fp8(P) + b2)
  k_mlp<128, 8, false, false, false, false, 2>
      <<<GRID_MLP, 256, 0, stream>>>(hbuf, nullptr, Wp2b, nullptr, nullptr, Pq, N);
  k_gather_q<128><<<N / 4, 256, 0, stream>>>(Pq, rowptr, colidx, gb, N);
  k_mlp<128, 8, false, true, false, true, 0>
      <<<GRID_MLP, 256, 0, stream>>>(hbuf, nullptr, Wp2a, b2, gb, out, N);
}

// Round 11
// 604.469 us; speedup vs baseline: 1.6838x; 1.1392x over previous
//
#include <hip/hip_runtime.h>

// GraphSAGE 2-layer inference, MI355X — round 11.
// = round 10 minus its mistakes:
//   - histogram DELETED: deg recovered from edge_val (= 1/deg(src)) via plain
//     stores (benign identical-value race) — no atomics, no fused-kernel poison
//   - cvt back to pure streaming (bf16+fp8 mirrors + deg zero only)
//   - cursor pre-initialized to rowptr in k_scan3 -> fill atomic returns the
//     absolute colidx slot (one fewer random load per edge)
//   - 4-pass src-ranged fill kept (L2 write locality)
// Inputs: x[N,256] f32, edge_src[E] i32, edge_dst[E] i32, edge_val[E] f32,
//         W1[512,256] f32, b1[256] f32, W2[512,128] f32, b2[128] f32.
// Output: [N,128] f32 (row L2-normalized).

#define N_NODES 100000
#define N_EDGES 3200000
#define DF      256          // feature dim (D_IN == D_HID)
#define NRANGE  4            // src-range passes for the CSR fill

typedef __bf16 bf16x8 __attribute__((ext_vector_type(8)));
typedef float  f32x4  __attribute__((ext_vector_type(4)));
typedef float  f32x2  __attribute__((ext_vector_type(2)));

__device__ __forceinline__ ushort f2bf(float f){   // RTNE f32 -> bf16
  uint u = __float_as_uint(f);
  u += 0x7fffu + ((u >> 16) & 1u);
  return (ushort)(u >> 16);
}
__device__ __forceinline__ float bflo(uint u){ return __uint_as_float(u << 16); }
__device__ __forceinline__ float bfhi(uint u){ return __uint_as_float(u & 0xffff0000u); }

// -------- f32 -> bf16 + fp8 mirrors (pure streaming; zeroes deg on the side) --------

__global__ void k_cvt(const float4* __restrict__ x4, uint4* __restrict__ outb,
                      uint2* __restrict__ outq, int n8, int* __restrict__ deg, int nz){
  int i = blockIdx.x * blockDim.x + threadIdx.x;
  if(i < nz) deg[i] = 0;
  if(i >= n8) return;
  const float4 p = x4[2*i], q = x4[2*i+1];
  uint4 o;
  o.x = (uint)f2bf(p.x) | ((uint)f2bf(p.y) << 16);
  o.y = (uint)f2bf(p.z) | ((uint)f2bf(p.w) << 16);
  o.z = (uint)f2bf(q.x) | ((uint)f2bf(q.y) << 16);
  o.w = (uint)f2bf(q.z) | ((uint)f2bf(q.w) << 16);
  outb[i] = o;
  uint w0 = __builtin_amdgcn_cvt_pk_fp8_f32(p.x, p.y, 0u, false);
  w0      = __builtin_amdgcn_cvt_pk_fp8_f32(p.z, p.w, w0, true);
  uint w1 = __builtin_amdgcn_cvt_pk_fp8_f32(q.x, q.y, 0u, false);
  w1      = __builtin_amdgcn_cvt_pk_fp8_f32(q.z, q.w, w1, true);
  outq[i] = make_uint2(w0, w1);
}

// -------- degree from edge_val: deg(src) == round(1/edge_val) exactly --------
// Plain store — all edges of a row write the identical value (benign race).

__global__ void k_deg(const int* __restrict__ esrc, const float* __restrict__ eval,
                      int* __restrict__ deg, int E){
  int i = blockIdx.x * blockDim.x + threadIdx.x;
  if(i < E){
    const int   s = __builtin_nontemporal_load(&esrc[i]);
    const float v = __builtin_nontemporal_load(&eval[i]);
    deg[s] = (int)roundf(1.0f / v);
  }
}

// ------------------------- CSR scan -------------------------

__global__ void k_scan1(const int* __restrict__ deg, int* __restrict__ rowptr,
                        int* __restrict__ partials, int n){
  __shared__ int s[256];
  const int t = threadIdx.x;
  const int base = blockIdx.x * 1024 + t * 4;
  int v[4], run[4];
  #pragma unroll
  for(int j = 0; j < 4; j++) v[j] = (base + j < n) ? deg[base + j] : 0;
  int sum = 0;
  #pragma unroll
  for(int j = 0; j < 4; j++){ run[j] = sum; sum += v[j]; }
  s[t] = sum;
  __syncthreads();
  for(int off = 1; off < 256; off <<= 1){
    int x = (t >= off) ? s[t - off] : 0;
    __syncthreads();
    s[t] += x;
    __syncthreads();
  }
  const int texcl = s[t] - sum;
  #pragma unroll
  for(int j = 0; j < 4; j++) if(base + j < n) rowptr[base + j] = texcl + run[j];
  if(t == 255) partials[blockIdx.x] = s[255];
}

__global__ void k_scan2(int* __restrict__ partials, int nb,
                        int* __restrict__ rowptr, int n, int E){
  __shared__ int s[128];
  const int t = threadIdx.x;
  int v = (t < nb) ? partials[t] : 0;
  s[t] = v;
  __syncthreads();
  for(int off = 1; off < 128; off <<= 1){
    int x = (t >= off) ? s[t - off] : 0;
    __syncthreads();
    s[t] += x;
    __syncthreads();
  }
  if(t < nb) partials[t] = s[t] - v;
  if(t == 0) rowptr[n] = E;
}

// finalize rowptr AND initialize cursor to the row start (absolute slots)

__global__ void k_scan3(int* __restrict__ rowptr, const int* __restrict__ partials,
                        int* __restrict__ cursor, int n){
  int i = blockIdx.x * blockDim.x + threadIdx.x;
  if(i < n){
    const int v = rowptr[i] + partials[i >> 10];
    rowptr[i] = v;
    cursor[i] = v;
  }
}

// ---------------- CSR fill: direct atomic scatter, src-ranged ----------------
// cursor holds absolute positions -> per edge: load src -> atomic -> store.
// Pass r handles src in [lo,hi): live colidx window ~3.2MB stays L2-resident.

__global__ void k_fill(const int* __restrict__ src, const int* __restrict__ dst,
                       int* __restrict__ cursor, int* __restrict__ col,
                       int E, int lo, int hi){
  int i = blockIdx.x * blockDim.x + threadIdx.x;
  if(i < E){
    const int r = src[i];
    if(r >= lo && r < hi){
      const int p = atomicAdd(&cursor[r], 1);
      col[p] = dst[i];
    }
  }
}

// ------------------- W fragment pack (all three, one dispatch) -------------------
// B-fragment for mfma_f32_16x16x32_bf16: lane l holds B[k0+(l>>4)*8+i][col0+(l&15)], i=0..7.

__device__ __forceinline__ void pack_frag(const float* __restrict__ W, uint4* __restrict__ Wp,
                                          int DOUT, int ksteps, int krow0, int tid){
  const int l   = tid & 63;
  const int s   = (tid >> 6) % ksteps;
  const int n   = tid / (64 * ksteps);
  const int grp = l >> 4, li = l & 15;
  const int col = n * 16 + li;
  ushort b[8];
  #pragma unroll
  for(int i = 0; i < 8; i++){
    const int k = krow0 + s * 32 + grp * 8 + i;
    b[i] = f2bf(W[(size_t)k * DOUT + col]);
  }
  uint4 o;
  o.x = (uint)b[0] | ((uint)b[1] << 16);
  o.y = (uint)b[2] | ((uint)b[3] << 16);
  o.z = (uint)b[4] | ((uint)b[5] << 16);
  o.w = (uint)b[6] | ((uint)b[7] << 16);
  Wp[tid] = o;
}

__global__ void k_packall(const float* __restrict__ W1, const float* __restrict__ W2,
                          uint4* __restrict__ Wp1, uint4* __restrict__ Wp2a,
                          uint4* __restrict__ Wp2b){
  const int tid = blockIdx.x * blockDim.x + threadIdx.x;
  if(tid < 16384)       pack_frag(W1, Wp1,  256, 16,   0, tid);           // 16*16*64
  else if(tid < 20480)  pack_frag(W2, Wp2a, 128,  8,   0, tid - 16384);   //  8* 8*64
  else if(tid < 24576)  pack_frag(W2, Wp2b, 128,  8, 256, tid - 20480);   //  8* 8*64
}

// ------------------ gather from fp8 table (mean -> bf16, elementwise) ------------------
// One wave per node; RB = row bytes (256 or 128). LPR = RB/16 lanes per row,
// EPG = 64/LPR edges per group, 4 uint4 loads in flight. v_cvt_pk_f32_fp8 decode.

template<int RB>
__global__ __launch_bounds__(256)
void k_gather_q(const uchar* __restrict__ xq, const int* __restrict__ rowptr,
                const int* __restrict__ colidx, ushort* __restrict__ nbuf, int Nn){
  constexpr int LPR = RB / 16;
  constexpr int EPG = 64 / LPR;
  const int node = (blockIdx.x * blockDim.x + threadIdx.x) >> 6;
  const int lane = threadIdx.x & 63;
  if(node >= Nn) return;
  const int half = lane / LPR;
  const int li   = lane % LPR;
  const int s0 = rowptr[node];
  const int s1 = rowptr[node + 1];
  const float invd = (s1 > s0) ? (1.0f / (float)(s1 - s0)) : 0.0f;
  const uint cmax = (uint)(Nn - 1);
  float a[16];
  #pragma unroll
  for(int i = 0; i < 16; i++) a[i] = 0.f;

  #define DECODE_ACC(v)                                                        \
    {                                                                          \
      const uint uu[4] = {(v).x, (v).y, (v).z, (v).w};                         \
      _Pragma("unroll")                                                        \
      for(int m = 0; m < 4; m++){                                              \
        f32x2 lo = __builtin_amdgcn_cvt_pk_f32_fp8(uu[m], false);              \
        f32x2 hi = __builtin_amdgcn_cvt_pk_f32_fp8(uu[m], true);               \
        a[m*4+0] += lo.x; a[m*4+1] += lo.y;                                    \
        a[m*4+2] += hi.x; a[m*4+3] += hi.y;                                    \
      }                                                                        \
    }

  int e = s0;
  for(; e + 4 * EPG <= s1; e += 4 * EPG){
    uint c[4];
    #pragma unroll
    for(int j = 0; j < 4; j++)
      c[j] = min((uint)__builtin_nontemporal_load(&colidx[e + j * EPG + half]), cmax);
    uint4 v[4];
    #pragma unroll
    for(int j = 0; j < 4; j++) v[j] = *(const uint4*)(xq + (size_t)c[j] * RB + li * 16);
    #pragma unroll
    for(int j = 0; j < 4; j++) DECODE_ACC(v[j]);
  }
  for(; e + EPG <= s1; e += EPG){
    const uint c = min((uint)__builtin_nontemporal_load(&colidx[e + half]), cmax);
    const uint4 v = *(const uint4*)(xq + (size_t)c * RB + li * 16);
    DECODE_ACC(v);
  }
  if(half < s1 - e){
    const uint c = min((uint)__builtin_nontemporal_load(&colidx[e + half]), cmax);
    const uint4 v = *(const uint4*)(xq + (size_t)c * RB + li * 16);
    DECODE_ACC(v);
  }
  #undef DECODE_ACC

  #pragma unroll
  for(int off = LPR; off < 64; off <<= 1)
    #pragma unroll
    for(int i = 0; i < 16; i++) a[i] += __shfl_xor(a[i], off);

  if(lane < LPR){
    uint4 o1, o2;
    o1.x = (uint)f2bf(a[ 0]*invd) | ((uint)f2bf(a[ 1]*invd) << 16);
    o1.y = (uint)f2bf(a[ 2]*invd) | ((uint)f2bf(a[ 3]*invd) << 16);
    o1.z = (uint)f2bf(a[ 4]*invd) | ((uint)f2bf(a[ 5]*invd) << 16);
    o1.w = (uint)f2bf(a[ 6]*invd) | ((uint)f2bf(a[ 7]*invd) << 16);
    o2.x = (uint)f2bf(a[ 8]*invd) | ((uint)f2bf(a[ 9]*invd) << 16);
    o2.y = (uint)f2bf(a[10]*invd) | ((uint)f2bf(a[11]*invd) << 16);
    o2.z = (uint)f2bf(a[12]*invd) | ((uint)f2bf(a[13]*invd) << 16);
    o2.w = (uint)f2bf(a[14]*invd) | ((uint)f2bf(a[15]*invd) << 16);
    ushort* p = nbuf + (size_t)node * RB + li * 16;
    *(uint4*)(p)     = o1;
    *(uint4*)(p + 8) = o2;
  }
}

// ------------------------- MFMA MLP / projection -------------------------
// Per wave: 16 nodes. A-frag lane l holds A[l&15][s*32+(l>>4)*8+i]. TWOSRC: first
// KS/2 k-steps from A0, rest from A1 (concat). B from Wp (L2-hot). C layout:
// col=lane&15, row=(lane>>4)*4+reg. OMODE: 0=f32, 1=bf16, 2=fp8 permuted
// (col n*16+li stored at byte li*8+n). ADDG adds gathered bf16 term (permuted).

template<int DOUT, int KS, bool TWOSRC, bool ADDG, bool RELU, bool NORM, int OMODE>
__launch_bounds__(256, 2)
__global__ void k_mlp(const ushort* __restrict__ A0, const ushort* __restrict__ A1,
                      const uint4* __restrict__ Wp, const float* __restrict__ bias,
                      const ushort* __restrict__ g,
                      void* __restrict__ outp, int Nn)
{
  constexpr int NT   = DOUT / 16;
  constexpr int DIMA = TWOSRC ? KS * 16 : KS * 32;
  const int l     = threadIdx.x & 63;
  const int w     = threadIdx.x >> 6;
  const int nodeb = blockIdx.x * 64 + w * 16;
  const int grp   = l >> 4;
  const int li    = l & 15;

  const int rowL = min(nodeb + li, Nn - 1);
  uint4 a[KS];
  if(TWOSRC){
    const ushort* xr = A0 + (size_t)rowL * DIMA;
    const ushort* nr = A1 + (size_t)rowL * DIMA;
    #pragma unroll
    for(int s = 0; s < KS/2; s++) a[s]        = *(const uint4*)(xr + s * 32 + grp * 8);
    #pragma unroll
    for(int s = 0; s < KS/2; s++) a[s + KS/2] = *(const uint4*)(nr + s * 32 + grp * 8);
  } else {
    const ushort* xr = A0 + (size_t)rowL * DIMA;
    #pragma unroll
    for(int s = 0; s < KS; s++) a[s] = *(const uint4*)(xr + s * 32 + grp * 8);
  }

  f32x4 acc[NT];
  #pragma unroll
  for(int n = 0; n < NT; n++){
    f32x4 c = {0.f, 0.f, 0.f, 0.f};
    #pragma unroll
    for(int s = 0; s < KS; s++){
      const uint4 b = Wp[(size_t)(n * KS + s) * 64 + l];
      c = __builtin_amdgcn_mfma_f32_16x16x32_bf16(
            __builtin_bit_cast(bf16x8, a[s]),
            __builtin_bit_cast(bf16x8, b), c, 0, 0, 0);
    }
    acc[n] = c;
  }

  if(NORM){
    #pragma unroll
    for(int n = 0; n < NT; n++){
      const float bv = bias[n * 16 + li];
      acc[n][0] += bv; acc[n][1] += bv; acc[n][2] += bv; acc[n][3] += bv;
    }
  }

  if(ADDG){   // permuted layout: byte j=li*8+n <-> col n*16+li; 8 bf16 = one uint4
    #pragma unroll
    for(int r = 0; r < 4; r++){
      const int rowg = min(nodeb + grp * 4 + r, Nn - 1);
      const uint4 gv = *(const uint4*)(g + (size_t)rowg * DOUT + li * 8);
      acc[0][r] += bflo(gv.x); acc[1][r] += bfhi(gv.x);
      acc[2][r] += bflo(gv.y); acc[3][r] += bfhi(gv.y);
      acc[4][r] += bflo(gv.z); acc[5][r] += bfhi(gv.z);
      acc[6][r] += bflo(gv.w); acc[7][r] += bfhi(gv.w);
    }
  }

  float rn[4] = {1.f, 1.f, 1.f, 1.f};
  if(NORM){
    #pragma unroll
    for(int r = 0; r < 4; r++){
      float ss = 0.f;
      #pragma unroll
      for(int n = 0; n < NT; n++) ss = fmaf(acc[n][r], acc[n][r], ss);
      ss += __shfl_xor(ss, 1);
      ss += __shfl_xor(ss, 2);
      ss += __shfl_xor(ss, 4);
      ss += __shfl_xor(ss, 8);
      rn[r] = 1.0f / fmaxf(sqrtf(ss), 1e-12f);
    }
  }

  #pragma unroll
  for(int r = 0; r < 4; r++){
    const int node = nodeb + grp * 4 + r;
    if(node < Nn){
      if(OMODE == 2){   // fp8, permuted: 8 cols -> 8 consecutive bytes
        uint w0 = __builtin_amdgcn_cvt_pk_fp8_f32(acc[0][r], acc[1][r], 0u, false);
        w0      = __builtin_amdgcn_cvt_pk_fp8_f32(acc[2][r], acc[3][r], w0, true);
        uint w1 = __builtin_amdgcn_cvt_pk_fp8_f32(acc[4][r], acc[5][r], 0u, false);
        w1      = __builtin_amdgcn_cvt_pk_fp8_f32(acc[6][r], acc[7][r], w1, true);
        *(uint2*)((uchar*)outp + (size_t)node * DOUT + li * 8) = make_uint2(w0, w1);
      } else {
        #pragma unroll
        for(int n = 0; n < NT; n++){
          float y = acc[n][r];
          if(NORM) y *= rn[r];
          if(RELU) y = fmaxf(y, 0.0f);
          const size_t idx = (size_t)node * DOUT + n * 16 + li;
          if(OMODE == 1) ((ushort*)outp)[idx] = f2bf(y);
          else           ((float*)outp)[idx]  = y;
        }
      }
    }
  }
}

// ------------------------- host launch -------------------------

extern "C" void kernel_launch(void* const* d_in, const int* in_sizes, int n_in,
                              void* d_out, int out_size, void* d_ws, size_t ws_size,
                              hipStream_t stream) {
  const float* x    = (const float*)d_in[0];
  const int*   esrc = (const int*)  d_in[1];
  const int*   edst = (const int*)  d_in[2];
  const float* eval = (const float*)d_in[3];   // == 1/deg(src) — used to skip the histogram
  const float* W1   = (const float*)d_in[4];
  const float* b1   = (const float*)d_in[5];
  const float* W2   = (const float*)d_in[6];
  const float* b2   = (const float*)d_in[7];
  float* out = (float*)d_out;

  const int N = N_NODES, E = N_EDGES;

  char* ws = (char*)d_ws;
  size_t off = 0;
  auto alloc = [&](size_t bytes) -> void* {
    void* p = ws + off;
    off += (bytes + 255) & ~(size_t)255;
    return p;
  };
  int*    deg      = (int*)   alloc((size_t)N * 4);
  int*    rowptr   = (int*)   alloc((size_t)(N + 1) * 4);
  int*    cursor   = (int*)   alloc((size_t)N * 4);
  int*    partials = (int*)   alloc(512);
  int*    colidx   = (int*)   alloc((size_t)E * 4);
  ushort* xbuf     = (ushort*)alloc((size_t)N * DF * 2);   // bf16 mirror of x
  uchar*  xq       = (uchar*) alloc((size_t)N * DF);       // fp8 e4m3 mirror of x
  ushort* hbuf     = (ushort*)alloc((size_t)N * DF * 2);   // bf16 h (layer-1 out)
  ushort* nbuf     = (ushort*)alloc((size_t)N * DF * 2);   // layer1 neigh; reused as Pq|gb
  uint4*  Wp1      = (uint4*) alloc((size_t)16 * 16 * 64 * 16);  // W1: NT=16, KS=16
  uint4*  Wp2a     = (uint4*) alloc((size_t) 8 *  8 * 64 * 16);  // W2 rows 0..255
  uint4*  Wp2b     = (uint4*) alloc((size_t) 8 *  8 * 64 * 16);  // W2 rows 256..511
  if(off > ws_size) return;

  uchar*  Pq = (uchar*)nbuf;                 // [N,128] fp8, permuted cols
  ushort* gb = nbuf + (size_t)N * 64;        // [N,128] bf16 gathered P

  const int NBLK_SCAN = (N + 1023) / 1024;   // 98
  const int n8 = N * DF / 8;                 // 3.2M

  // mirrors of x (zeroes deg on the side), degree from edge_val, W packs
  k_cvt  <<<(n8 + 255) / 256, 256, 0, stream>>>((const float4*)x, (uint4*)xbuf,
                                                (uint2*)xq, n8, deg, N);
  k_deg  <<<(E + 255) / 256, 256, 0, stream>>>(esrc, eval, deg, E);
  k_packall<<<96, 256, 0, stream>>>(W1, W2, Wp1, Wp2a, Wp2b);

  // CSR: scan (cursor = rowptr), then src-ranged absolute-slot fill
  k_scan1<<<NBLK_SCAN,       256, 0, stream>>>(deg, rowptr, partials, N);
  k_scan2<<<1,               128, 0, stream>>>(partials, NBLK_SCAN, rowptr, N, E);
  k_scan3<<<(N + 255) / 256, 256, 0, stream>>>(rowptr, partials, cursor, N);
  const int RSPAN = N / NRANGE;   // 25000
  for(int r = 0; r < NRANGE; r++)
    k_fill<<<(E + 255) / 256, 256, 0, stream>>>(esrc, edst, cursor, colidx,
                                                E, r * RSPAN, (r + 1) * RSPAN);

  const int GRID_MLP = (N + 63) / 64;   // 1563, tail-guarded

  // ---- layer 1: h = relu(normalize([x | mean_fp8(x)] @ W1 + b1))
  k_gather_q<256><<<N / 4, 256, 0, stream>>>(xq, rowptr, colidx, nbuf, N);
  k_mlp<256, 16, true, false, true, true, 1>
      <<<GRID_MLP, 256, 0, stream>>>(xbuf, nbuf, Wp1, b1, nullptr, hbuf, N);

  // ---- layer 2 (project-then-aggregate, P in fp8 permuted layout):
  //   P = h @ W2_bot ; out = normalize(h @ W2_top + mean_fp8(P) + b2)
  k_mlp<128, 8, false, false, false, false, 2>
      <<<GRID_MLP, 256, 0, stream>>>(hbuf, nullptr, Wp2b, nullptr, nullptr, Pq, N);
  k_gather_q<128><<<N / 4, 256, 0, stream>>>(Pq, rowptr, colidx, gb, N);
  k_mlp<128, 8, false, true, false, true, 0>
      <<<GRID_MLP, 256, 0, stream>>>(hbuf, nullptr, Wp2a, b2, gb, out, N);
}

// Round 12
// 580.920 us; speedup vs baseline: 1.7521x; 1.0405x over previous
//
#include <hip/hip_runtime.h>

// GraphSAGE 2-layer inference, MI355X — round 12.
// = round 11 plus:
//   - gathers accumulate in f32x2 (v_pk_add_f32) — 33% fewer VALU ops in decode
//   - P-projection fused into mlp1 via padded-LDS transpose (one fewer dispatch,
//     one fewer 51MB hbuf pass). Pq moved to its own buffer (no nbuf aliasing).
// Inputs: x[N,256] f32, edge_src[E] i32, edge_dst[E] i32, edge_val[E] f32,
//         W1[512,256] f32, b1[256] f32, W2[512,128] f32, b2[128] f32.
// Output: [N,128] f32 (row L2-normalized).

#define N_NODES 100000
#define N_EDGES 3200000
#define DF      256          // feature dim (D_IN == D_HID)
#define NRANGE  4            // src-range passes for the CSR fill

typedef __bf16 bf16x8 __attribute__((ext_vector_type(8)));
typedef float  f32x4  __attribute__((ext_vector_type(4)));
typedef float  f32x2  __attribute__((ext_vector_type(2)));

__device__ __forceinline__ ushort f2bf(float f){   // RTNE f32 -> bf16
  uint u = __float_as_uint(f);
  u += 0x7fffu + ((u >> 16) & 1u);
  return (ushort)(u >> 16);
}
__device__ __forceinline__ float bflo(uint u){ return __uint_as_float(u << 16); }
__device__ __forceinline__ float bfhi(uint u){ return __uint_as_float(u & 0xffff0000u); }

// -------- f32 -> bf16 + fp8 mirrors (pure streaming; zeroes deg on the side) --------

__global__ void k_cvt(const float4* __restrict__ x4, uint4* __restrict__ outb,
                      uint2* __restrict__ outq, int n8, int* __restrict__ deg, int nz){
  int i = blockIdx.x * blockDim.x + threadIdx.x;
  if(i < nz) deg[i] = 0;
  if(i >= n8) return;
  const float4 p = x4[2*i], q = x4[2*i+1];
  uint4 o;
  o.x = (uint)f2bf(p.x) | ((uint)f2bf(p.y) << 16);
  o.y = (uint)f2bf(p.z) | ((uint)f2bf(p.w) << 16);
  o.z = (uint)f2bf(q.x) | ((uint)f2bf(q.y) << 16);
  o.w = (uint)f2bf(q.z) | ((uint)f2bf(q.w) << 16);
  outb[i] = o;
  uint w0 = __builtin_amdgcn_cvt_pk_fp8_f32(p.x, p.y, 0u, false);
  w0      = __builtin_amdgcn_cvt_pk_fp8_f32(p.z, p.w, w0, true);
  uint w1 = __builtin_amdgcn_cvt_pk_fp8_f32(q.x, q.y, 0u, false);
  w1      = __builtin_amdgcn_cvt_pk_fp8_f32(q.z, q.w, w1, true);
  outq[i] = make_uint2(w0, w1);
}

// -------- degree from edge_val: deg(src) == round(1/edge_val) exactly --------

__global__ void k_deg(const int* __restrict__ esrc, const float* __restrict__ eval,
                      int* __restrict__ deg, int E){
  int i = blockIdx.x * blockDim.x + threadIdx.x;
  if(i < E){
    const int   s = __builtin_nontemporal_load(&esrc[i]);
    const float v = __builtin_nontemporal_load(&eval[i]);
    deg[s] = (int)roundf(1.0f / v);
  }
}

// ------------------------- CSR scan -------------------------

__global__ void k_scan1(const int* __restrict__ deg, int* __restrict__ rowptr,
                        int* __restrict__ partials, int n){
  __shared__ int s[256];
  const int t = threadIdx.x;
  const int base = blockIdx.x * 1024 + t * 4;
  int v[4], run[4];
  #pragma unroll
  for(int j = 0; j < 4; j++) v[j] = (base + j < n) ? deg[base + j] : 0;
  int sum = 0;
  #pragma unroll
  for(int j = 0; j < 4; j++){ run[j] = sum; sum += v[j]; }
  s[t] = sum;
  __syncthreads();
  for(int off = 1; off < 256; off <<= 1){
    int x = (t >= off) ? s[t - off] : 0;
    __syncthreads();
    s[t] += x;
    __syncthreads();
  }
  const int texcl = s[t] - sum;
  #pragma unroll
  for(int j = 0; j < 4; j++) if(base + j < n) rowptr[base + j] = texcl + run[j];
  if(t == 255) partials[blockIdx.x] = s[255];
}

__global__ void k_scan2(int* __restrict__ partials, int nb,
                        int* __restrict__ rowptr, int n, int E){
  __shared__ int s[128];
  const int t = threadIdx.x;
  int v = (t < nb) ? partials[t] : 0;
  s[t] = v;
  __syncthreads();
  for(int off = 1; off < 128; off <<= 1){
    int x = (t >= off) ? s[t - off] : 0;
    __syncthreads();
    s[t] += x;
    __syncthreads();
  }
  if(t < nb) partials[t] = s[t] - v;
  if(t == 0) rowptr[n] = E;
}

__global__ void k_scan3(int* __restrict__ rowptr, const int* __restrict__ partials,
                        int* __restrict__ cursor, int n){
  int i = blockIdx.x * blockDim.x + threadIdx.x;
  if(i < n){
    const int v = rowptr[i] + partials[i >> 10];
    rowptr[i] = v;
    cursor[i] = v;
  }
}

// ---------------- CSR fill: direct atomic scatter, src-ranged ----------------

__global__ void k_fill(const int* __restrict__ src, const int* __restrict__ dst,
                       int* __restrict__ cursor, int* __restrict__ col,
                       int E, int lo, int hi){
  int i = blockIdx.x * blockDim.x + threadIdx.x;
  if(i < E){
    const int r = src[i];
    if(r >= lo && r < hi){
      const int p = atomicAdd(&cursor[r], 1);
      col[p] = dst[i];
    }
  }
}

// ------------------- W fragment pack (all three, one dispatch) -------------------
// B-fragment for mfma_f32_16x16x32_bf16: lane l holds B[k0+(l>>4)*8+i][col0+(l&15)], i=0..7.

__device__ __forceinline__ void pack_frag(const float* __restrict__ W, uint4* __restrict__ Wp,
                                          int DOUT, int ksteps, int krow0, int tid){
  const int l   = tid & 63;
  const int s   = (tid >> 6) % ksteps;
  const int n   = tid / (64 * ksteps);
  const int grp = l >> 4, li = l & 15;
  const int col = n * 16 + li;
  ushort b[8];
  #pragma unroll
  for(int i = 0; i < 8; i++){
    const int k = krow0 + s * 32 + grp * 8 + i;
    b[i] = f2bf(W[(size_t)k * DOUT + col]);
  }
  uint4 o;
  o.x = (uint)b[0] | ((uint)b[1] << 16);
  o.y = (uint)b[2] | ((uint)b[3] << 16);
  o.z = (uint)b[4] | ((uint)b[5] << 16);
  o.w = (uint)b[6] | ((uint)b[7] << 16);
  Wp[tid] = o;
}

__global__ void k_packall(const float* __restrict__ W1, const float* __restrict__ W2,
                          uint4* __restrict__ Wp1, uint4* __restrict__ Wp2a,
                          uint4* __restrict__ Wp2b){
  const int tid = blockIdx.x * blockDim.x + threadIdx.x;
  if(tid < 16384)       pack_frag(W1, Wp1,  256, 16,   0, tid);           // 16*16*64
  else if(tid < 20480)  pack_frag(W2, Wp2a, 128,  8,   0, tid - 16384);   //  8* 8*64
  else if(tid < 24576)  pack_frag(W2, Wp2b, 128,  8, 256, tid - 20480);   //  8* 8*64
}

// ------------------ gather from fp8 table (mean -> bf16, elementwise) ------------------
// One wave per node; RB = row bytes (256 or 128). LPR = RB/16 lanes per row,
// EPG = 64/LPR edges per group, 4 uint4 loads in flight. v_cvt_pk_f32_fp8 decode,
// f32x2 packed accumulate (v_pk_add_f32).

template<int RB>
__global__ __launch_bounds__(256)
void k_gather_q(const uchar* __restrict__ xq, const int* __restrict__ rowptr,
                const int* __restrict__ colidx, ushort* __restrict__ nbuf, int Nn){
  constexpr int LPR = RB / 16;
  constexpr int EPG = 64 / LPR;
  const int node = (blockIdx.x * blockDim.x + threadIdx.x) >> 6;
  const int lane = threadIdx.x & 63;
  if(node >= Nn) return;
  const int half = lane / LPR;
  const int li   = lane % LPR;
  const int s0 = rowptr[node];
  const int s1 = rowptr[node + 1];
  const float invd = (s1 > s0) ? (1.0f / (float)(s1 - s0)) : 0.0f;
  const uint cmax = (uint)(Nn - 1);
  f32x2 a2[8];
  #pragma unroll
  for(int i = 0; i < 8; i++) a2[i] = (f32x2){0.f, 0.f};

  #define DECODE_ACC(v)                                                        \
    {                                                                          \
      const uint uu[4] = {(v).x, (v).y, (v).z, (v).w};                         \
      _Pragma("unroll")                                                        \
      for(int m = 0; m < 4; m++){                                              \
        f32x2 lo = __builtin_amdgcn_cvt_pk_f32_fp8(uu[m], false);              \
        f32x2 hi = __builtin_amdgcn_cvt_pk_f32_fp8(uu[m], true);               \
        a2[2*m]   += lo;                                                       \
        a2[2*m+1] += hi;                                                       \
      }                                                                        \
    }

  int e = s0;
  for(; e + 4 * EPG <= s1; e += 4 * EPG){
    uint c[4];
    #pragma unroll
    for(int j = 0; j < 4; j++)
      c[j] = min((uint)__builtin_nontemporal_load(&colidx[e + j * EPG + half]), cmax);
    uint4 v[4];
    #pragma unroll
    for(int j = 0; j < 4; j++) v[j] = *(const uint4*)(xq + (size_t)c[j] * RB + li * 16);
    #pragma unroll
    for(int j = 0; j < 4; j++) DECODE_ACC(v[j]);
  }
  for(; e + EPG <= s1; e += EPG){
    const uint c = min((uint)__builtin_nontemporal_load(&colidx[e + half]), cmax);
    const uint4 v = *(const uint4*)(xq + (size_t)c * RB + li * 16);
    DECODE_ACC(v);
  }
  if(half < s1 - e){
    const uint c = min((uint)__builtin_nontemporal_load(&colidx[e + half]), cmax);
    const uint4 v = *(const uint4*)(xq + (size_t)c * RB + li * 16);
    DECODE_ACC(v);
  }
  #undef DECODE_ACC

  float a[16];
  #pragma unroll
  for(int i = 0; i < 8; i++){ a[2*i] = a2[i].x; a[2*i+1] = a2[i].y; }

  #pragma unroll
  for(int off = LPR; off < 64; off <<= 1)
    #pragma unroll
    for(int i = 0; i < 16; i++) a[i] += __shfl_xor(a[i], off);

  if(lane < LPR){
    uint4 o1, o2;
    o1.x = (uint)f2bf(a[ 0]*invd) | ((uint)f2bf(a[ 1]*invd) << 16);
    o1.y = (uint)f2bf(a[ 2]*invd) | ((uint)f2bf(a[ 3]*invd) << 16);
    o1.z = (uint)f2bf(a[ 4]*invd) | ((uint)f2bf(a[ 5]*invd) << 16);
    o1.w = (uint)f2bf(a[ 6]*invd) | ((uint)f2bf(a[ 7]*invd) << 16);
    o2.x = (uint)f2bf(a[ 8]*invd) | ((uint)f2bf(a[ 9]*invd) << 16);
    o2.y = (uint)f2bf(a[10]*invd) | ((uint)f2bf(a[11]*invd) << 16);
    o2.z = (uint)f2bf(a[12]*invd) | ((uint)f2bf(a[13]*invd) << 16);
    o2.w = (uint)f2bf(a[14]*invd) | ((uint)f2bf(a[15]*invd) << 16);
    ushort* p = nbuf + (size_t)node * RB + li * 16;
    *(uint4*)(p)     = o1;
    *(uint4*)(p + 8) = o2;
  }
}

// --------------- fused layer-1 MLP + P projection ---------------
// Phase 1: h = relu(normalize([x|neigh] @ W1 + b1)) — 16 nodes/wave, 256 MFMA.
// h (bf16, post-round) goes to hbuf AND a padded LDS tile [16][264] (528B row
// stride breaks the 512B power-of-2 bank conflict). Phase 2: re-read A-frags
// from LDS, P = h @ W2_bot (64 MFMA), store fp8-permuted Pq. Bit-identical to
// the former separate k_mlp2-proj (same bf16 h input).

__launch_bounds__(256, 2)
__global__ void k_mlp1p(const ushort* __restrict__ xb, const ushort* __restrict__ nb,
                        const uint4* __restrict__ Wp1, const float* __restrict__ b1,
                        const uint4* __restrict__ Wp2b,
                        ushort* __restrict__ hbuf, uchar* __restrict__ Pq, int Nn)
{
  __shared__ ushort hT[4][16][264];   // 33792 B
  const int l     = threadIdx.x & 63;
  const int w     = threadIdx.x >> 6;
  const int nodeb = blockIdx.x * 64 + w * 16;
  const int grp   = l >> 4;
  const int li    = l & 15;

  const int rowL = min(nodeb + li, Nn - 1);
  const ushort* xr = xb + (size_t)rowL * DF;
  const ushort* nr = nb + (size_t)rowL * DF;
  uint4 a[16];
  #pragma unroll
  for(int s = 0; s < 8; s++) a[s]     = *(const uint4*)(xr + s * 32 + grp * 8);
  #pragma unroll
  for(int s = 0; s < 8; s++) a[s + 8] = *(const uint4*)(nr + s * 32 + grp * 8);

  f32x4 acc[16];
  #pragma unroll
  for(int n = 0; n < 16; n++){
    f32x4 c = {0.f, 0.f, 0.f, 0.f};
    #pragma unroll
    for(int s = 0; s < 16; s++){
      const uint4 b = Wp1[(size_t)(n * 16 + s) * 64 + l];
      c = __builtin_amdgcn_mfma_f32_16x16x32_bf16(
            __builtin_bit_cast(bf16x8, a[s]),
            __builtin_bit_cast(bf16x8, b), c, 0, 0, 0);
    }
    acc[n] = c;
  }

  #pragma unroll
  for(int n = 0; n < 16; n++){
    const float bv = b1[n * 16 + li];
    acc[n][0] += bv; acc[n][1] += bv; acc[n][2] += bv; acc[n][3] += bv;
  }

  #pragma unroll
  for(int r = 0; r < 4; r++){
    float ss = 0.f;
    #pragma unroll
    for(int n = 0; n < 16; n++) ss = fmaf(acc[n][r], acc[n][r], ss);
    ss += __shfl_xor(ss, 1);
    ss += __shfl_xor(ss, 2);
    ss += __shfl_xor(ss, 4);
    ss += __shfl_xor(ss, 8);
    const float rn = 1.0f / fmaxf(sqrtf(ss), 1e-12f);
    const int row  = grp * 4 + r;
    const int node = nodeb + row;
    #pragma unroll
    for(int n = 0; n < 16; n++){
      const ushort hv = f2bf(fmaxf(acc[n][r] * rn, 0.0f));
      hT[w][row][n * 16 + li] = hv;
      if(node < Nn) hbuf[(size_t)node * DF + n * 16 + li] = hv;
    }
  }
  __syncthreads();

  // ---- phase 2: P = h @ W2_bot, fp8-permuted store
  uint4 pa[8];
  #pragma unroll
  for(int s = 0; s < 8; s++) pa[s] = *(const uint4*)&hT[w][li][s * 32 + grp * 8];

  f32x4 pacc[8];
  #pragma unroll
  for(int n = 0; n < 8; n++){
    f32x4 c = {0.f, 0.f, 0.f, 0.f};
    #pragma unroll
    for(int s = 0; s < 8; s++){
      const uint4 b = Wp2b[(size_t)(n * 8 + s) * 64 + l];
      c = __builtin_amdgcn_mfma_f32_16x16x32_bf16(
            __builtin_bit_cast(bf16x8, pa[s]),
            __builtin_bit_cast(bf16x8, b), c, 0, 0, 0);
    }
    pacc[n] = c;
  }

  #pragma unroll
  for(int r = 0; r < 4; r++){
    const int node = nodeb + grp * 4 + r;
    if(node < Nn){
      uint w0 = __builtin_amdgcn_cvt_pk_fp8_f32(pacc[0][r], pacc[1][r], 0u, false);
      w0      = __builtin_amdgcn_cvt_pk_fp8_f32(pacc[2][r], pacc[3][r], w0, true);
      uint w1 = __builtin_amdgcn_cvt_pk_fp8_f32(pacc[4][r], pacc[5][r], 0u, false);
      w1      = __builtin_amdgcn_cvt_pk_fp8_f32(pacc[6][r], pacc[7][r], w1, true);
      *(uint2*)(Pq + (size_t)node * 128 + li * 8) = make_uint2(w0, w1);
    }
  }
}

// ------------------------- MFMA MLP (layer-2 final) -------------------------
// As round 11; only the <128,8,false,true,false,true,0> instantiation is used.

template<int DOUT, int KS, bool TWOSRC, bool ADDG, bool RELU, bool NORM, int OMODE>
__launch_bounds__(256, 2)
__global__ void k_mlp(const ushort* __restrict__ A0, const ushort* __restrict__ A1,
                      const uint4* __restrict__ Wp, const float* __restrict__ bias,
                      const ushort* __restrict__ g,
                      void* __restrict__ outp, int Nn)
{
  constexpr int NT   = DOUT / 16;
  constexpr int DIMA = TWOSRC ? KS * 16 : KS * 32;
  const int l     = threadIdx.x & 63;
  const int w     = threadIdx.x >> 6;
  const int nodeb = blockIdx.x * 64 + w * 16;
  const int grp   = l >> 4;
  const int li    = l & 15;

  const int rowL = min(nodeb + li, Nn - 1);
  uint4 a[KS];
  if(TWOSRC){
    const ushort* xr = A0 + (size_t)rowL * DIMA;
    const ushort* nr = A1 + (size_t)rowL * DIMA;
    #pragma unroll
    for(int s = 0; s < KS/2; s++) a[s]        = *(const uint4*)(xr + s * 32 + grp * 8);
    #pragma unroll
    for(int s = 0; s < KS/2; s++) a[s + KS/2] = *(const uint4*)(nr + s * 32 + grp * 8);
  } else {
    const ushort* xr = A0 + (size_t)rowL * DIMA;
    #pragma unroll
    for(int s = 0; s < KS; s++) a[s] = *(const uint4*)(xr + s * 32 + grp * 8);
  }

  f32x4 acc[NT];
  #pragma unroll
  for(int n = 0; n < NT; n++){
    f32x4 c = {0.f, 0.f, 0.f, 0.f};
    #pragma unroll
    for(int s = 0; s < KS; s++){
      const uint4 b = Wp[(size_t)(n * KS + s) * 64 + l];
      c = __builtin_amdgcn_mfma_f32_16x16x32_bf16(
            __builtin_bit_cast(bf16x8, a[s]),
            __builtin_bit_cast(bf16x8, b), c, 0, 0, 0);
    }
    acc[n] = c;
  }

  if(NORM){
    #pragma unroll
    for(int n = 0; n < NT; n++){
      const float bv = bias[n * 16 + li];
      acc[n][0] += bv; acc[n][1] += bv; acc[n][2] += bv; acc[n][3] += bv;
    }
  }

  if(ADDG){   // permuted layout: byte j=li*8+n <-> col n*16+li; 8 bf16 = one uint4
    #pragma unroll
    for(int r = 0; r < 4; r++){
      const int rowg = min(nodeb + grp * 4 + r, Nn - 1);
      const uint4 gv = *(const uint4*)(g + (size_t)rowg * DOUT + li * 8);
      acc[0][r] += bflo(gv.x); acc[1][r] += bfhi(gv.x);
      acc[2][r] += bflo(gv.y); acc[3][r] += bfhi(gv.y);
      acc[4][r] += bflo(gv.z); acc[5][r] += bfhi(gv.z);
      acc[6][r] += bflo(gv.w); acc[7][r] += bfhi(gv.w);
    }
  }

  float rn[4] = {1.f, 1.f, 1.f, 1.f};
  if(NORM){
    #pragma unroll
    for(int r = 0; r < 4; r++){
      float ss = 0.f;
      #pragma unroll
      for(int n = 0; n < NT; n++) ss = fmaf(acc[n][r], acc[n][r], ss);
      ss += __shfl_xor(ss, 1);
      ss += __shfl_xor(ss, 2);
      ss += __shfl_xor(ss, 4);
      ss += __shfl_xor(ss, 8);
      rn[r] = 1.0f / fmaxf(sqrtf(ss), 1e-12f);
    }
  }

  #pragma unroll
  for(int r = 0; r < 4; r++){
    const int node = nodeb + grp * 4 + r;
    if(node < Nn){
      if(OMODE == 2){
        uint w0 = __builtin_amdgcn_cvt_pk_fp8_f32(acc[0][r], acc[1][r], 0u, false);
        w0      = __builtin_amdgcn_cvt_pk_fp8_f32(acc[2][r], acc[3][r], w0, true);
        uint w1 = __builtin_amdgcn_cvt_pk_fp8_f32(acc[4][r], acc[5][r], 0u, false);
        w1      = __builtin_amdgcn_cvt_pk_fp8_f32(acc[6][r], acc[7][r], w1, true);
        *(uint2*)((uchar*)outp + (size_t)node * DOUT + li * 8) = make_uint2(w0, w1);
      } else {
        #pragma unroll
        for(int n = 0; n < NT; n++){
          float y = acc[n][r];
          if(NORM) y *= rn[r];
          if(RELU) y = fmaxf(y, 0.0f);
          const size_t idx = (size_t)node * DOUT + n * 16 + li;
          if(OMODE == 1) ((ushort*)outp)[idx] = f2bf(y);
          else           ((float*)outp)[idx]  = y;
        }
      }
    }
  }
}

// ------------------------- host launch -------------------------

extern "C" void kernel_launch(void* const* d_in, const int* in_sizes, int n_in,
                              void* d_out, int out_size, void* d_ws, size_t ws_size,
                              hipStream_t stream) {
  const float* x    = (const float*)d_in[0];
  const int*   esrc = (const int*)  d_in[1];
  const int*   edst = (const int*)  d_in[2];
  const float* eval = (const float*)d_in[3];   // == 1/deg(src) — replaces the histogram
  const float* W1   = (const float*)d_in[4];
  const float* b1   = (const float*)d_in[5];
  const float* W2   = (const float*)d_in[6];
  const float* b2   = (const float*)d_in[7];
  float* out = (float*)d_out;

  const int N = N_NODES, E = N_EDGES;

  char* ws = (char*)d_ws;
  size_t off = 0;
  auto alloc = [&](size_t bytes) -> void* {
    void* p = ws + off;
    off += (bytes + 255) & ~(size_t)255;
    return p;
  };
  int*    deg      = (int*)   alloc((size_t)N * 4);
  int*    rowptr   = (int*)   alloc((size_t)(N + 1) * 4);
  int*    cursor   = (int*)   alloc((size_t)N * 4);
  int*    partials = (int*)   alloc(512);
  int*    colidx   = (int*)   alloc((size_t)E * 4);
  ushort* xbuf     = (ushort*)alloc((size_t)N * DF * 2);   // bf16 mirror of x
  uchar*  xq       = (uchar*) alloc((size_t)N * DF);       // fp8 e4m3 mirror of x
  ushort* hbuf     = (ushort*)alloc((size_t)N * DF * 2);   // bf16 h (layer-1 out)
  ushort* nbuf     = (ushort*)alloc((size_t)N * DF * 2);   // layer1 neigh; reused as gb
  uchar*  Pq       = (uchar*) alloc((size_t)N * 128);      // fp8 P, permuted cols (own buffer!)
  uint4*  Wp1      = (uint4*) alloc((size_t)16 * 16 * 64 * 16);  // W1: NT=16, KS=16
  uint4*  Wp2a     = (uint4*) alloc((size_t) 8 *  8 * 64 * 16);  // W2 rows 0..255
  uint4*  Wp2b     = (uint4*) alloc((size_t) 8 *  8 * 64 * 16);  // W2 rows 256..511
  if(off > ws_size) return;

  ushort* gb = nbuf;                         // [N,128] bf16 gathered P (nbuf dead by then)

  const int NBLK_SCAN = (N + 1023) / 1024;   // 98
  const int n8 = N * DF / 8;                 // 3.2M

  // mirrors of x (zeroes deg on the side), degree from edge_val, W packs
  k_cvt  <<<(n8 + 255) / 256, 256, 0, stream>>>((const float4*)x, (uint4*)xbuf,
                                                (uint2*)xq, n8, deg, N);
  k_deg  <<<(E + 255) / 256, 256, 0, stream>>>(esrc, eval, deg, E);
  k_packall<<<96, 256, 0, stream>>>(W1, W2, Wp1, Wp2a, Wp2b);

  // CSR: scan (cursor = rowptr), then src-ranged absolute-slot fill
  k_scan1<<<NBLK_SCAN,       256, 0, stream>>>(deg, rowptr, partials, N);
  k_scan2<<<1,               128, 0, stream>>>(partials, NBLK_SCAN, rowptr, N, E);
  k_scan3<<<(N + 255) / 256, 256, 0, stream>>>(rowptr, partials, cursor, N);
  const int RSPAN = N / NRANGE;   // 25000
  for(int r = 0; r < NRANGE; r++)
    k_fill<<<(E + 255) / 256, 256, 0, stream>>>(esrc, edst, cursor, colidx,
                                                E, r * RSPAN, (r + 1) * RSPAN);

  const int GRID_MLP = (N + 63) / 64;   // 1563, tail-guarded

  // ---- layer 1 (+ fused P projection):
  //   h = relu(normalize([x | mean_fp8(x)] @ W1 + b1)); P = h @ W2_bot (fp8 perm)
  k_gather_q<256><<<N / 4, 256, 0, stream>>>(xq, rowptr, colidx, nbuf, N);
  k_mlp1p<<<GRID_MLP, 256, 0, stream>>>(xbuf, nbuf, Wp1, b1, Wp2b, hbuf, Pq, N);

  // ---- layer 2: out = normalize(h @ W2_top + mean_fp8(P) + b2)
  k_gather_q<128><<<N / 4, 256, 0, stream>>>(Pq, rowptr, colidx, gb, N);
  k_mlp<128, 8, false, true, false, true, 0>
      <<<GRID_MLP, 256, 0, stream>>>(hbuf, nullptr, Wp2a, b2, gb, out, N);
}